// Round 4
// baseline (1256.345 us; speedup 1.0000x reference)
//
#include <hip/hip_runtime.h>
#include <math.h>

#define N_NODES 100000
#define N_EDGES 1600000
#define N_IN 256
#define N_OUT 64

#define RPB 128                                   // rows per bucket
#define NBUCKETS ((N_NODES + RPB - 1) / RPB)      // 782

// ws layout (bytes). Total ~25.6 MB.
#define WS_HBF    0           // bf16 h [100000][64]            12,800,000 B
#define WS_WT     12800000    // bf16 W^T swizzled image            32,768 B
#define WS_BCNT   12832768    // int bucket counts[782]              4,096 B
#define WS_BOFF   12836864    // int bucket offs[783]                4,096 B
#define WS_BCUR   12840960    // int bucket cursors[782]             4,096 B
#define WS_EDGES  12845056    // int2 bucketed edges[1600000]   12,800,000 B

typedef __attribute__((ext_vector_type(8))) __bf16 bf16x8;
typedef __attribute__((ext_vector_type(4))) float f32x4;

static __device__ __forceinline__ unsigned short f2bf(float f) {
    union { float f; unsigned int u; } a; a.f = f;
    unsigned int u = a.u;
    return (unsigned short)((u + 0x7FFFu + ((u >> 16) & 1u)) >> 16); // RNE
}
static __device__ __forceinline__ float bf2f(unsigned short h) {
    union { unsigned int u; float f; } a; a.u = ((unsigned int)h) << 16;
    return a.f;
}

// ---------------------------------------------------------------------------
// W [256][64] fp32 -> W^T bf16 swizzled LDS image (see gemm_kernel).
// ---------------------------------------------------------------------------
__global__ __launch_bounds__(256) void wconv_kernel(const float* __restrict__ W,
                                                    unsigned short* __restrict__ wt) {
    const int g = blockIdx.x * 256 + threadIdx.x;   // 0..16383
    const int k = g >> 6, n = g & 63;
    const unsigned short v = f2bf(W[k * N_OUT + n]);
    const unsigned m = (unsigned)k >> 3;
    const unsigned byte = (unsigned)n * 512u + ((m ^ ((unsigned)n & 7u)) << 4);
    wt[byte / 2 + (k & 7)] = v;
}

// ---------------------------------------------------------------------------
// GEMM h = x @ W + b via v_mfma_f32_16x16x32_bf16, h stored bf16.
// block = 256 (4 waves), each wave owns 16 rows x 64 cols (4 col-tiles).
// ---------------------------------------------------------------------------
__global__ __launch_bounds__(256) void gemm_kernel(const float* __restrict__ x,
                                                   const float4* __restrict__ wt,
                                                   const float* __restrict__ bias,
                                                   unsigned short* __restrict__ hbf) {
    __shared__ unsigned short Wlds[N_IN * N_OUT]; // 32 KB, swizzled image
    const int t = threadIdx.x;
#pragma unroll
    for (int i = 0; i < 8; ++i)
        reinterpret_cast<float4*>(Wlds)[t + i * 256] = wt[t + i * 256];
    __syncthreads();

    const int wave = t >> 6, lane = t & 63;
    const int lrow = lane & 15, q = lane >> 4;
    const int r0 = blockIdx.x * 64 + wave * 16;
    int row = r0 + lrow;
    if (row >= N_NODES) row = N_NODES - 1;       // clamp loads; stores guarded
    const float* xp = x + (size_t)row * N_IN + q * 8;

    const char* ldsb = reinterpret_cast<const char*>(Wlds);
    unsigned colbase[4], colx[4];
#pragma unroll
    for (int c = 0; c < 4; ++c) {
        const unsigned col = c * 16 + lrow;
        colbase[c] = col * 512u;
        colx[c] = col & 7u;
    }

    f32x4 acc[4];
#pragma unroll
    for (int c = 0; c < 4; ++c) acc[c] = (f32x4){0.f, 0.f, 0.f, 0.f};

#pragma unroll
    for (int ks = 0; ks < 8; ++ks) {
        const float4 a0 = *reinterpret_cast<const float4*>(xp + ks * 32);
        const float4 a1 = *reinterpret_cast<const float4*>(xp + ks * 32 + 4);
        union { bf16x8 v; unsigned short u[8]; } af;
        af.u[0] = f2bf(a0.x); af.u[1] = f2bf(a0.y);
        af.u[2] = f2bf(a0.z); af.u[3] = f2bf(a0.w);
        af.u[4] = f2bf(a1.x); af.u[5] = f2bf(a1.y);
        af.u[6] = f2bf(a1.z); af.u[7] = f2bf(a1.w);
        const unsigned m = ks * 4 + q;
#pragma unroll
        for (int c = 0; c < 4; ++c) {
            const unsigned byte = colbase[c] + ((m ^ colx[c]) << 4);
            const bf16x8 bv = *reinterpret_cast<const bf16x8*>(ldsb + byte);
            acc[c] = __builtin_amdgcn_mfma_f32_16x16x32_bf16(af.v, bv, acc[c], 0, 0, 0);
        }
    }

#pragma unroll
    for (int c = 0; c < 4; ++c) {
        const int col = c * 16 + lrow;
        const float bv = bias[col];
#pragma unroll
        for (int mm = 0; mm < 4; ++mm) {
            const int rr = r0 + q * 4 + mm;
            if (rr < N_NODES)
                hbf[(size_t)rr * N_OUT + col] = f2bf(acc[c][mm] + bv);
        }
    }
}

// ------------------------- bucket histogram --------------------------------
__global__ __launch_bounds__(256) void bhist_kernel(const int* __restrict__ er,
                                                    int* __restrict__ bcnt) {
    __shared__ int lh[NBUCKETS];
    const int t = threadIdx.x;
    for (int i = t; i < NBUCKETS; i += 256) lh[i] = 0;
    __syncthreads();
    for (int e = blockIdx.x * 256 + t; e < N_EDGES; e += gridDim.x * 256)
        atomicAdd(&lh[er[e] >> 7], 1);
    __syncthreads();
    for (int i = t; i < NBUCKETS; i += 256)
        if (lh[i]) atomicAdd(&bcnt[i], lh[i]);
}

// ------------------------- bucket scan (1 block) ---------------------------
__global__ __launch_bounds__(1024) void bscan_kernel(const int* __restrict__ bcnt,
                                                     int* __restrict__ boffs,
                                                     int* __restrict__ bcur) {
    __shared__ int s[1024];
    const int t = threadIdx.x;
    const int v = (t < NBUCKETS) ? bcnt[t] : 0;
    s[t] = v; __syncthreads();
#pragma unroll
    for (int d = 1; d < 1024; d <<= 1) {
        const int u = (t >= d) ? s[t - d] : 0;
        __syncthreads();
        s[t] += u;
        __syncthreads();
    }
    if (t < NBUCKETS) {
        const int o = s[t] - v;     // exclusive
        boffs[t] = o;
        bcur[t] = o;
    }
    if (t == 0) boffs[NBUCKETS] = N_EDGES;
}

// ------------------------- bucket scatter ----------------------------------
// pack: meta = col | (rowlocal << 17); 8B write into sequentially-filling
// per-bucket region (good line locality, ~13 MB HBM write).
__global__ __launch_bounds__(256) void bscatter_kernel(const int* __restrict__ er,
                                                       const int* __restrict__ ec,
                                                       const float* __restrict__ ev,
                                                       int* __restrict__ bcur,
                                                       int2* __restrict__ edges) {
    const int e = blockIdx.x * 256 + threadIdx.x;   // grid exact: 6250*256
    const int r = er[e];
    const int b = r >> 7;
    const int pos = atomicAdd(&bcur[b], 1);
    edges[pos] = make_int2(ec[e] | ((r & 127) << 17), __float_as_int(ev[e]));
}

// ------------------- bucket aggregation + fused ELU ------------------------
// one block per bucket; 32 KB LDS fp32 accum [128 rows][64 cols].
// wave handles one edge across 64 lanes (lane = col); 4-deep ILP;
// ds_add_f32 LDS atomics (bank = lane&31 -> 2-way, free).
__global__ __launch_bounds__(256) void bagg_kernel(const int* __restrict__ boffs,
                                                   const int2* __restrict__ edges,
                                                   const unsigned short* __restrict__ hbf,
                                                   float* __restrict__ out) {
    __shared__ float accum[RPB * N_OUT];   // 32 KB
    const int b = blockIdx.x;
    const int t = threadIdx.x;
    const int wave = t >> 6, lane = t & 63;
#pragma unroll
    for (int i = 0; i < (RPB * N_OUT) / (256 * 4); ++i)
        reinterpret_cast<float4*>(accum)[t + i * 256] = (float4){0.f, 0.f, 0.f, 0.f};
    __syncthreads();

    const int s = boffs[b], e = boffs[b + 1];
    int i = s + wave;
    for (; i + 12 < e; i += 16) {
        const int2 e0 = edges[i];
        const int2 e1 = edges[i + 4];
        const int2 e2 = edges[i + 8];
        const int2 e3 = edges[i + 12];
        const float h0 = bf2f(hbf[(size_t)(e0.x & 0x1FFFF) * N_OUT + lane]);
        const float h1 = bf2f(hbf[(size_t)(e1.x & 0x1FFFF) * N_OUT + lane]);
        const float h2 = bf2f(hbf[(size_t)(e2.x & 0x1FFFF) * N_OUT + lane]);
        const float h3 = bf2f(hbf[(size_t)(e3.x & 0x1FFFF) * N_OUT + lane]);
        atomicAdd(&accum[(e0.x >> 17) * N_OUT + lane], __int_as_float(e0.y) * h0);
        atomicAdd(&accum[(e1.x >> 17) * N_OUT + lane], __int_as_float(e1.y) * h1);
        atomicAdd(&accum[(e2.x >> 17) * N_OUT + lane], __int_as_float(e2.y) * h2);
        atomicAdd(&accum[(e3.x >> 17) * N_OUT + lane], __int_as_float(e3.y) * h3);
    }
    for (; i < e; i += 4) {
        const int2 cv = edges[i];
        const float hv = bf2f(hbf[(size_t)(cv.x & 0x1FFFF) * N_OUT + lane]);
        atomicAdd(&accum[(cv.x >> 17) * N_OUT + lane], __int_as_float(cv.y) * hv);
    }
    __syncthreads();

    const int row0 = b * RPB;
    for (int r = wave; r < RPB; r += 4) {
        const int row = row0 + r;
        if (row < N_NODES) {
            const float v = accum[r * N_OUT + lane];
            out[(size_t)row * N_OUT + lane] = v > 0.f ? v : expf(v) - 1.f;
        }
    }
}

extern "C" void kernel_launch(void* const* d_in, const int* in_sizes, int n_in,
                              void* d_out, int out_size, void* d_ws, size_t ws_size,
                              hipStream_t stream) {
    const float* x  = (const float*)d_in[0];
    const int*   er = (const int*)d_in[1];
    const int*   ec = (const int*)d_in[2];
    const float* ev = (const float*)d_in[3];
    const float* W  = (const float*)d_in[4];
    const float* b  = (const float*)d_in[5];
    float* out = (float*)d_out;
    char* ws = (char*)d_ws;

    unsigned short* hbf = (unsigned short*)(ws + WS_HBF);
    unsigned short* wt  = (unsigned short*)(ws + WS_WT);
    int*  bcnt  = (int*)(ws + WS_BCNT);
    int*  boffs = (int*)(ws + WS_BOFF);
    int*  bcur  = (int*)(ws + WS_BCUR);
    int2* edges = (int2*)(ws + WS_EDGES);

    hipMemsetAsync(bcnt, 0, NBUCKETS * sizeof(int), stream);

    bhist_kernel<<<400, 256, 0, stream>>>(er, bcnt);
    bscan_kernel<<<1, 1024, 0, stream>>>(bcnt, boffs, bcur);
    bscatter_kernel<<<N_EDGES / 256, 256, 0, stream>>>(er, ec, ev, bcur, edges);
    wconv_kernel<<<64, 256, 0, stream>>>(W, wt);
    gemm_kernel<<<(N_NODES + 63) / 64, 256, 0, stream>>>(x, (const float4*)wt, b, hbf);
    bagg_kernel<<<NBUCKETS, 256, 0, stream>>>(boffs, edges, hbf, out);
}

// Round 5
// 519.942 us; speedup vs baseline: 2.4163x; 2.4163x over previous
//
#include <hip/hip_runtime.h>
#include <math.h>

#define N_NODES 100000
#define N_EDGES 1600000
#define N_IN 256
#define N_OUT 64

#define RPB 64                                    // rows per bucket
#define NBUCKETS ((N_NODES + RPB - 1) / RPB)      // 1563
#define CAP 1536                                  // staged edges per chunk (6*256)

// ws layout (bytes). Total ~25.7 MB.
#define WS_HBF    0           // bf16 h [100000][64]            12,800,000 B
#define WS_WT     12800000    // bf16 W^T swizzled image            32,768 B
#define WS_BCNT   12832768    // int bucket counts[1563]             8,192 B
#define WS_BOFF   12840960    // int bucket offs[1564]               8,192 B
#define WS_BCUR   12849152    // int bucket cursors[1563]            8,192 B
#define WS_EDGES  12857344    // int2 bucketed edges[1600000]   12,800,000 B

typedef __attribute__((ext_vector_type(8))) __bf16 bf16x8;
typedef __attribute__((ext_vector_type(4))) float f32x4;

static __device__ __forceinline__ unsigned short f2bf(float f) {
    union { float f; unsigned int u; } a; a.f = f;
    unsigned int u = a.u;
    return (unsigned short)((u + 0x7FFFu + ((u >> 16) & 1u)) >> 16); // RNE
}
static __device__ __forceinline__ float bf2f(unsigned short h) {
    union { unsigned int u; float f; } a; a.u = ((unsigned int)h) << 16;
    return a.f;
}

// ---------------------------------------------------------------------------
// W [256][64] fp32 -> W^T bf16 swizzled LDS image (see gemm_kernel).
// ---------------------------------------------------------------------------
__global__ __launch_bounds__(256) void wconv_kernel(const float* __restrict__ W,
                                                    unsigned short* __restrict__ wt) {
    const int g = blockIdx.x * 256 + threadIdx.x;   // 0..16383
    const int k = g >> 6, n = g & 63;
    const unsigned short v = f2bf(W[k * N_OUT + n]);
    const unsigned m = (unsigned)k >> 3;
    const unsigned byte = (unsigned)n * 512u + ((m ^ ((unsigned)n & 7u)) << 4);
    wt[byte / 2 + (k & 7)] = v;
}

// ---------------------------------------------------------------------------
// GEMM h = x @ W + b via v_mfma_f32_16x16x32_bf16, h stored bf16.
// block = 256 (4 waves), each wave owns 16 rows x 64 cols (4 col-tiles).
// ---------------------------------------------------------------------------
__global__ __launch_bounds__(256) void gemm_kernel(const float* __restrict__ x,
                                                   const float4* __restrict__ wt,
                                                   const float* __restrict__ bias,
                                                   unsigned short* __restrict__ hbf) {
    __shared__ unsigned short Wlds[N_IN * N_OUT]; // 32 KB, swizzled image
    const int t = threadIdx.x;
#pragma unroll
    for (int i = 0; i < 8; ++i)
        reinterpret_cast<float4*>(Wlds)[t + i * 256] = wt[t + i * 256];
    __syncthreads();

    const int wave = t >> 6, lane = t & 63;
    const int lrow = lane & 15, q = lane >> 4;
    const int r0 = blockIdx.x * 64 + wave * 16;
    int row = r0 + lrow;
    if (row >= N_NODES) row = N_NODES - 1;       // clamp loads; stores guarded
    const float* xp = x + (size_t)row * N_IN + q * 8;

    const char* ldsb = reinterpret_cast<const char*>(Wlds);
    unsigned colbase[4], colx[4];
#pragma unroll
    for (int c = 0; c < 4; ++c) {
        const unsigned col = c * 16 + lrow;
        colbase[c] = col * 512u;
        colx[c] = col & 7u;
    }

    f32x4 acc[4];
#pragma unroll
    for (int c = 0; c < 4; ++c) acc[c] = (f32x4){0.f, 0.f, 0.f, 0.f};

#pragma unroll
    for (int ks = 0; ks < 8; ++ks) {
        const float4 a0 = *reinterpret_cast<const float4*>(xp + ks * 32);
        const float4 a1 = *reinterpret_cast<const float4*>(xp + ks * 32 + 4);
        union { bf16x8 v; unsigned short u[8]; } af;
        af.u[0] = f2bf(a0.x); af.u[1] = f2bf(a0.y);
        af.u[2] = f2bf(a0.z); af.u[3] = f2bf(a0.w);
        af.u[4] = f2bf(a1.x); af.u[5] = f2bf(a1.y);
        af.u[6] = f2bf(a1.z); af.u[7] = f2bf(a1.w);
        const unsigned m = ks * 4 + q;
#pragma unroll
        for (int c = 0; c < 4; ++c) {
            const unsigned byte = colbase[c] + ((m ^ colx[c]) << 4);
            const bf16x8 bv = *reinterpret_cast<const bf16x8*>(ldsb + byte);
            acc[c] = __builtin_amdgcn_mfma_f32_16x16x32_bf16(af.v, bv, acc[c], 0, 0, 0);
        }
    }

#pragma unroll
    for (int c = 0; c < 4; ++c) {
        const int col = c * 16 + lrow;
        const float bv = bias[col];
#pragma unroll
        for (int mm = 0; mm < 4; ++mm) {
            const int rr = r0 + q * 4 + mm;
            if (rr < N_NODES)
                hbf[(size_t)rr * N_OUT + col] = f2bf(acc[c][mm] + bv);
        }
    }
}

// ------------------------- bucket histogram --------------------------------
__global__ __launch_bounds__(256) void bhist_kernel(const int* __restrict__ er,
                                                    int* __restrict__ bcnt) {
    __shared__ int lh[NBUCKETS];
    const int t = threadIdx.x;
    for (int i = t; i < NBUCKETS; i += 256) lh[i] = 0;
    __syncthreads();
    for (int e = blockIdx.x * 256 + t; e < N_EDGES; e += gridDim.x * 256)
        atomicAdd(&lh[er[e] >> 6], 1);
    __syncthreads();
    for (int i = t; i < NBUCKETS; i += 256)
        if (lh[i]) atomicAdd(&bcnt[i], lh[i]);
}

// ------------------------- bucket scan (1 block) ---------------------------
// 1024 threads x 2 elements = 2048 slots >= 1563.
__global__ __launch_bounds__(1024) void bscan_kernel(const int* __restrict__ bcnt,
                                                     int* __restrict__ boffs,
                                                     int* __restrict__ bcur) {
    __shared__ int s[1024];
    const int t = threadIdx.x;
    const int i0 = 2 * t, i1 = 2 * t + 1;
    const int a = (i0 < NBUCKETS) ? bcnt[i0] : 0;
    const int bv = (i1 < NBUCKETS) ? bcnt[i1] : 0;
    s[t] = a + bv; __syncthreads();
#pragma unroll
    for (int d = 1; d < 1024; d <<= 1) {
        const int u = (t >= d) ? s[t - d] : 0;
        __syncthreads();
        s[t] += u;
        __syncthreads();
    }
    const int excl = s[t] - (a + bv);
    if (i0 < NBUCKETS) { boffs[i0] = excl;      bcur[i0] = excl; }
    if (i1 < NBUCKETS) { boffs[i1] = excl + a;  bcur[i1] = excl + a; }
    if (t == 0) boffs[NBUCKETS] = N_EDGES;
}

// ------------------------- bucket scatter ----------------------------------
// pack: meta = col | (rowlocal << 17); 8B write into sequentially-filling
// per-bucket region (line locality: ~1563 active 64B frontiers, L2-hot).
__global__ __launch_bounds__(256) void bscatter_kernel(const int* __restrict__ er,
                                                       const int* __restrict__ ec,
                                                       const float* __restrict__ ev,
                                                       int* __restrict__ bcur,
                                                       int2* __restrict__ edges) {
    const int e = blockIdx.x * 256 + threadIdx.x;   // grid exact: 6250*256
    const int r = er[e];
    const int b = r >> 6;
    const int pos = atomicAdd(&bcur[b], 1);
    edges[pos] = make_int2(ec[e] | ((r & 63) << 17), __float_as_int(ev[e]));
}

// ------------------- bucket aggregation + fused ELU ------------------------
// one block (4 waves) per 64-row bucket. Per chunk: stage <=1536 edges in
// LDS with an in-LDS counting sort by local row (int LDS atomics only),
// then wave w accumulates rows [w*16, w*16+16) in REGISTERS (no fp32
// atomics anywhere): per row, 4-deep-ILP gathers of h rows (L3-resident).
__global__ __launch_bounds__(256) void bagg_kernel(const int* __restrict__ boffs,
                                                   const int2* __restrict__ edges,
                                                   const unsigned short* __restrict__ hbf,
                                                   float* __restrict__ out) {
    __shared__ int2 sbuf[CAP];         // 12 KB
    __shared__ int rcnt[RPB];          // per-row histogram
    __shared__ int roff[RPB + 1];      // row offsets (inclusive scan, roff[0]=0)
    __shared__ int rcur[RPB];          // placement cursors
    const int b = blockIdx.x;
    const int t = threadIdx.x;
    const int wave = t >> 6, lane = t & 63;
    const int s = boffs[b], e = boffs[b + 1];

    float acc[16];
#pragma unroll
    for (int r = 0; r < 16; ++r) acc[r] = 0.f;

    for (int base = s; base < e; base += CAP) {
        const int cnt = min(CAP, e - base);
        // (A) zero hist
        if (t < RPB) rcnt[t] = 0;
        if (t == RPB) roff[0] = 0;
        __syncthreads();
        // (B) load edges to registers + histogram local rows
        int2 tmp[6];
#pragma unroll
        for (int j = 0; j < 6; ++j) {
            const int i = t + j * 256;
            if (i < cnt) {
                tmp[j] = edges[base + i];
                atomicAdd(&rcnt[tmp[j].x >> 17], 1);
            } else {
                tmp[j] = make_int2(0, 0);
            }
        }
        __syncthreads();
        // (C) wave-0 shfl scan of the 64 row counts
        if (t < 64) {
            const int v = rcnt[t];
            int inc = v;
#pragma unroll
            for (int d = 1; d < 64; d <<= 1) {
                const int u = __shfl_up(inc, d, 64);
                if (t >= d) inc += u;
            }
            roff[t + 1] = inc;
            rcur[t] = inc - v;    // exclusive start
        }
        __syncthreads();
        // (D) place edges into row-sorted LDS order
#pragma unroll
        for (int j = 0; j < 6; ++j) {
            const int i = t + j * 256;
            if (i < cnt) {
                const int rl = tmp[j].x >> 17;
                const int pos = atomicAdd(&rcur[rl], 1);
                sbuf[pos] = tmp[j];
            }
        }
        __syncthreads();
        // (E) accumulate: wave w owns rows w*16 .. w*16+15
#pragma unroll
        for (int rr = 0; rr < 16; ++rr) {
            const int r = wave * 16 + rr;
            const int i0 = roff[r], i1 = roff[r + 1];
            float a0 = 0.f, a1 = 0.f, a2 = 0.f, a3 = 0.f;
            int i = i0;
            for (; i + 4 <= i1; i += 4) {
                const int2 e0 = sbuf[i];
                const int2 e1 = sbuf[i + 1];
                const int2 e2 = sbuf[i + 2];
                const int2 e3 = sbuf[i + 3];
                const float h0 = bf2f(hbf[(size_t)(e0.x & 0x1FFFF) * N_OUT + lane]);
                const float h1 = bf2f(hbf[(size_t)(e1.x & 0x1FFFF) * N_OUT + lane]);
                const float h2 = bf2f(hbf[(size_t)(e2.x & 0x1FFFF) * N_OUT + lane]);
                const float h3 = bf2f(hbf[(size_t)(e3.x & 0x1FFFF) * N_OUT + lane]);
                a0 = fmaf(__int_as_float(e0.y), h0, a0);
                a1 = fmaf(__int_as_float(e1.y), h1, a1);
                a2 = fmaf(__int_as_float(e2.y), h2, a2);
                a3 = fmaf(__int_as_float(e3.y), h3, a3);
            }
            for (; i < i1; ++i) {
                const int2 cv = sbuf[i];
                a0 = fmaf(__int_as_float(cv.y),
                          bf2f(hbf[(size_t)(cv.x & 0x1FFFF) * N_OUT + lane]), a0);
            }
            acc[rr] += (a0 + a1) + (a2 + a3);
        }
        __syncthreads();   // sbuf/rcnt reused next chunk
    }

    // ELU + writeout (coalesced 256B per row-wave)
    const int row0 = b * RPB + wave * 16;
#pragma unroll
    for (int rr = 0; rr < 16; ++rr) {
        const int row = row0 + rr;
        if (row < N_NODES) {
            const float v = acc[rr];
            out[(size_t)row * N_OUT + lane] = v > 0.f ? v : expf(v) - 1.f;
        }
    }
}

extern "C" void kernel_launch(void* const* d_in, const int* in_sizes, int n_in,
                              void* d_out, int out_size, void* d_ws, size_t ws_size,
                              hipStream_t stream) {
    const float* x  = (const float*)d_in[0];
    const int*   er = (const int*)d_in[1];
    const int*   ec = (const int*)d_in[2];
    const float* ev = (const float*)d_in[3];
    const float* W  = (const float*)d_in[4];
    const float* b  = (const float*)d_in[5];
    float* out = (float*)d_out;
    char* ws = (char*)d_ws;

    unsigned short* hbf = (unsigned short*)(ws + WS_HBF);
    unsigned short* wt  = (unsigned short*)(ws + WS_WT);
    int*  bcnt  = (int*)(ws + WS_BCNT);
    int*  boffs = (int*)(ws + WS_BOFF);
    int*  bcur  = (int*)(ws + WS_BCUR);
    int2* edges = (int2*)(ws + WS_EDGES);

    hipMemsetAsync(bcnt, 0, NBUCKETS * sizeof(int), stream);

    bhist_kernel<<<400, 256, 0, stream>>>(er, bcnt);
    bscan_kernel<<<1, 1024, 0, stream>>>(bcnt, boffs, bcur);
    bscatter_kernel<<<N_EDGES / 256, 256, 0, stream>>>(er, ec, ev, bcur, edges);
    wconv_kernel<<<64, 256, 0, stream>>>(W, wt);
    gemm_kernel<<<(N_NODES + 63) / 64, 256, 0, stream>>>(x, (const float4*)wt, b, hbf);
    bagg_kernel<<<NBUCKETS, 256, 0, stream>>>(boffs, edges, hbf, out);
}

// Round 6
// 303.861 us; speedup vs baseline: 4.1346x; 1.7111x over previous
//
#include <hip/hip_runtime.h>
#include <math.h>

#define N_NODES 100000
#define N_EDGES 1600000
#define N_IN 256
#define N_OUT 64

#define RPB 64                                    // rows per bucket
#define NBUCKETS ((N_NODES + RPB - 1) / RPB)      // 1563
#define CAP 1536                                  // bagg staged edges per chunk
#define EPB 4096                                  // edges per scatter block
#define NBLK ((N_EDGES + EPB - 1) / EPB)          // 391

// ws layout (bytes). Total ~25.6 MB. histT aliases the edges region (it is
// dead before scat2 writes edges).
#define WS_HBF    0           // bf16 h [100000][64]            12,800,000 B
#define WS_WT     12800000    // bf16 W^T swizzled image            32,768 B
#define WS_GP     12832768    // u16 gposT[391][1563]            1,223,680 B
#define WS_BTOT   14056448    // int btot[1563]                      6,400 B
#define WS_BOFF   14062848    // int boffs[1564]                     6,400 B
#define WS_EDGES  14069248    // int2 bucketed edges[1600000]   12,800,000 B
#define WS_HT     WS_EDGES    // u16 histT[391][1563] (aliased)  1,222,266 B

typedef __attribute__((ext_vector_type(8))) __bf16 bf16x8;
typedef __attribute__((ext_vector_type(4))) float f32x4;

static __device__ __forceinline__ unsigned short f2bf(float f) {
    union { float f; unsigned int u; } a; a.f = f;
    unsigned int u = a.u;
    return (unsigned short)((u + 0x7FFFu + ((u >> 16) & 1u)) >> 16); // RNE
}
static __device__ __forceinline__ float bf2f(unsigned short h) {
    union { unsigned int u; float f; } a; a.u = ((unsigned int)h) << 16;
    return a.f;
}

// ---------------------------------------------------------------------------
// W [256][64] fp32 -> W^T bf16 swizzled LDS image (see gemm_kernel).
// ---------------------------------------------------------------------------
__global__ __launch_bounds__(256) void wconv_kernel(const float* __restrict__ W,
                                                    unsigned short* __restrict__ wt) {
    const int g = blockIdx.x * 256 + threadIdx.x;   // 0..16383
    const int k = g >> 6, n = g & 63;
    const unsigned short v = f2bf(W[k * N_OUT + n]);
    const unsigned m = (unsigned)k >> 3;
    const unsigned byte = (unsigned)n * 512u + ((m ^ ((unsigned)n & 7u)) << 4);
    wt[byte / 2 + (k & 7)] = v;
}

// ---------------------------------------------------------------------------
// GEMM h = x @ W + b via v_mfma_f32_16x16x32_bf16, h stored bf16.
// ---------------------------------------------------------------------------
__global__ __launch_bounds__(256) void gemm_kernel(const float* __restrict__ x,
                                                   const float4* __restrict__ wt,
                                                   const float* __restrict__ bias,
                                                   unsigned short* __restrict__ hbf) {
    __shared__ unsigned short Wlds[N_IN * N_OUT]; // 32 KB, swizzled image
    const int t = threadIdx.x;
#pragma unroll
    for (int i = 0; i < 8; ++i)
        reinterpret_cast<float4*>(Wlds)[t + i * 256] = wt[t + i * 256];
    __syncthreads();

    const int wave = t >> 6, lane = t & 63;
    const int lrow = lane & 15, q = lane >> 4;
    const int r0 = blockIdx.x * 64 + wave * 16;
    int row = r0 + lrow;
    if (row >= N_NODES) row = N_NODES - 1;       // clamp loads; stores guarded
    const float* xp = x + (size_t)row * N_IN + q * 8;

    const char* ldsb = reinterpret_cast<const char*>(Wlds);
    unsigned colbase[4], colx[4];
#pragma unroll
    for (int c = 0; c < 4; ++c) {
        const unsigned col = c * 16 + lrow;
        colbase[c] = col * 512u;
        colx[c] = col & 7u;
    }

    f32x4 acc[4];
#pragma unroll
    for (int c = 0; c < 4; ++c) acc[c] = (f32x4){0.f, 0.f, 0.f, 0.f};

#pragma unroll
    for (int ks = 0; ks < 8; ++ks) {
        const float4 a0 = *reinterpret_cast<const float4*>(xp + ks * 32);
        const float4 a1 = *reinterpret_cast<const float4*>(xp + ks * 32 + 4);
        union { bf16x8 v; unsigned short u[8]; } af;
        af.u[0] = f2bf(a0.x); af.u[1] = f2bf(a0.y);
        af.u[2] = f2bf(a0.z); af.u[3] = f2bf(a0.w);
        af.u[4] = f2bf(a1.x); af.u[5] = f2bf(a1.y);
        af.u[6] = f2bf(a1.z); af.u[7] = f2bf(a1.w);
        const unsigned m = ks * 4 + q;
#pragma unroll
        for (int c = 0; c < 4; ++c) {
            const unsigned byte = colbase[c] + ((m ^ colx[c]) << 4);
            const bf16x8 bv = *reinterpret_cast<const bf16x8*>(ldsb + byte);
            acc[c] = __builtin_amdgcn_mfma_f32_16x16x32_bf16(af.v, bv, acc[c], 0, 0, 0);
        }
    }

#pragma unroll
    for (int c = 0; c < 4; ++c) {
        const int col = c * 16 + lrow;
        const float bv = bias[col];
#pragma unroll
        for (int mm = 0; mm < 4; ++mm) {
            const int rr = r0 + q * 4 + mm;
            if (rr < N_NODES)
                hbf[(size_t)rr * N_OUT + col] = f2bf(acc[c][mm] + bv);
        }
    }
}

// ---------------- scatter pass 1: per-block bucket histogram ---------------
// block blk owns edges [blk*EPB, blk*EPB+EPB); writes u16 histT[blk][bucket].
__global__ __launch_bounds__(256) void hist2_kernel(const int* __restrict__ er,
                                                    unsigned short* __restrict__ histT) {
    __shared__ int lh[NBUCKETS];
    const int blk = blockIdx.x, t = threadIdx.x;
    const int e0 = blk * EPB;
    const int cnt = min(EPB, N_EDGES - e0);
    for (int i = t; i < NBUCKETS; i += 256) lh[i] = 0;
    __syncthreads();
#pragma unroll
    for (int j = 0; j < EPB / 256; ++j) {
        const int i = t + j * 256;
        if (i < cnt) atomicAdd(&lh[er[e0 + i] >> 6], 1);
    }
    __syncthreads();
    for (int i = t; i < NBUCKETS; i += 256)
        histT[(size_t)blk * NBUCKETS + i] = (unsigned short)lh[i];
}

// ---------------- scatter pass 2: within-bucket scan over blocks -----------
// one wave per bucket: exclusive scan of histT[*][b] over 391 blocks ->
// u16 gposT[blk][b] (within-bucket offset), int btot[b].
__global__ __launch_bounds__(256) void scanA_kernel(const unsigned short* __restrict__ histT,
                                                    unsigned short* __restrict__ gposT,
                                                    int* __restrict__ btot) {
    const int w = (int)((blockIdx.x * 256u + threadIdx.x) >> 6);  // bucket
    const int lane = threadIdx.x & 63;
    if (w >= NBUCKETS) return;                    // wave-uniform
    int running = 0;
#pragma unroll
    for (int c = 0; c < (NBLK + 63) / 64; ++c) {
        const int idx = c * 64 + lane;            // block index
        const int v = (idx < NBLK) ? (int)histT[(size_t)idx * NBUCKETS + w] : 0;
        int inc = v;
#pragma unroll
        for (int d = 1; d < 64; d <<= 1) {
            const int u = __shfl_up(inc, d, 64);
            if (lane >= d) inc += u;
        }
        if (idx < NBLK)
            gposT[(size_t)idx * NBUCKETS + w] = (unsigned short)(running + inc - v);
        running += __shfl(inc, 63, 64);
    }
    if (lane == 0) btot[w] = running;
}

// ---------------- scatter pass 3: cross-bucket scan (1 block) --------------
__global__ __launch_bounds__(1024) void bscan_kernel(const int* __restrict__ btot,
                                                     int* __restrict__ boffs) {
    __shared__ int s[1024];
    const int t = threadIdx.x;
    const int i0 = 2 * t, i1 = 2 * t + 1;
    const int a = (i0 < NBUCKETS) ? btot[i0] : 0;
    const int bv = (i1 < NBUCKETS) ? btot[i1] : 0;
    s[t] = a + bv; __syncthreads();
#pragma unroll
    for (int d = 1; d < 1024; d <<= 1) {
        const int u = (t >= d) ? s[t - d] : 0;
        __syncthreads();
        s[t] += u;
        __syncthreads();
    }
    const int excl = s[t] - (a + bv);
    if (i0 < NBUCKETS) boffs[i0] = excl;
    if (i1 < NBUCKETS) boffs[i1] = excl + a;
    if (t == 0) boffs[NBUCKETS] = N_EDGES;
}

// ---------------- scatter pass 4: LDS counting-sort + grouped write --------
// NO global atomics. Each block sorts its 4096 edges by bucket in LDS
// (int LDS atomics only), then lane-per-bucket copies each group to its
// exact precomputed global range (temporally clustered -> line-friendly).
__global__ __launch_bounds__(256) void scat2_kernel(const int* __restrict__ er,
                                                    const int* __restrict__ ec,
                                                    const float* __restrict__ ev,
                                                    const unsigned short* __restrict__ gposT,
                                                    const int* __restrict__ boffs,
                                                    int2* __restrict__ edges) {
    __shared__ int2 sbuf[EPB];          // 32 KB
    __shared__ int lhist[NBUCKETS];     // 6.25 KB
    __shared__ int lstart[NBUCKETS];    // 6.25 KB
    __shared__ int lcur[NBUCKETS];      // 6.25 KB
    __shared__ int csum[256];           // 1 KB
    const int blk = blockIdx.x, t = threadIdx.x;
    const int e0 = blk * EPB;
    const int cnt = min(EPB, N_EDGES - e0);

    for (int i = t; i < NBUCKETS; i += 256) lhist[i] = 0;
    __syncthreads();

    int2 tmp[EPB / 256];
    int  bkt[EPB / 256];
#pragma unroll
    for (int j = 0; j < EPB / 256; ++j) {
        const int i = t + j * 256;
        if (i < cnt) {
            const int r = er[e0 + i];
            bkt[j] = r >> 6;
            tmp[j] = make_int2(ec[e0 + i] | ((r & 63) << 17), __float_as_int(ev[e0 + i]));
            atomicAdd(&lhist[bkt[j]], 1);
        } else {
            bkt[j] = -1;
        }
    }
    __syncthreads();

    // block-local exclusive scan of lhist: coarse (7 buckets/thread) + H-S
    int own = 0;
#pragma unroll
    for (int k = 0; k < 7; ++k) {
        const int b = t * 7 + k;
        if (b < NBUCKETS) own += lhist[b];
    }
    csum[t] = own;
    __syncthreads();
    for (int d = 1; d < 256; d <<= 1) {
        const int u = (t >= d) ? csum[t - d] : 0;
        __syncthreads();
        csum[t] += u;
        __syncthreads();
    }
    {
        int excl = csum[t] - own;
#pragma unroll
        for (int k = 0; k < 7; ++k) {
            const int b = t * 7 + k;
            if (b < NBUCKETS) {
                lstart[b] = excl;
                lcur[b] = excl;
                excl += lhist[b];
            }
        }
    }
    __syncthreads();

    // place into bucket-sorted LDS order
#pragma unroll
    for (int j = 0; j < EPB / 256; ++j) {
        if (bkt[j] >= 0) {
            const int p = atomicAdd(&lcur[bkt[j]], 1);
            sbuf[p] = tmp[j];
        }
    }
    __syncthreads();

    // grouped copy-out: lane handles bucket b, sequential 8B writes
    for (int b = t; b < NBUCKETS; b += 256) {
        const int s = lstart[b];
        const int n = lcur[b] - s;
        if (n > 0) {
            const int g = boffs[b] + (int)gposT[(size_t)blk * NBUCKETS + b];
            for (int j = 0; j < n; ++j) edges[g + j] = sbuf[s + j];
        }
    }
}

// ------------------- bucket aggregation + fused ELU ------------------------
// one block (4 waves) per 64-row bucket; in-LDS counting sort by local row
// (int atomics only), register accumulation, 4-deep-ILP h gathers.
__global__ __launch_bounds__(256) void bagg_kernel(const int* __restrict__ boffs,
                                                   const int2* __restrict__ edges,
                                                   const unsigned short* __restrict__ hbf,
                                                   float* __restrict__ out) {
    __shared__ int2 sbuf[CAP];         // 12 KB
    __shared__ int rcnt[RPB];
    __shared__ int roff[RPB + 1];
    __shared__ int rcur[RPB];
    const int b = blockIdx.x;
    const int t = threadIdx.x;
    const int wave = t >> 6, lane = t & 63;
    const int s = boffs[b], e = boffs[b + 1];

    float acc[16];
#pragma unroll
    for (int r = 0; r < 16; ++r) acc[r] = 0.f;

    for (int base = s; base < e; base += CAP) {
        const int cnt = min(CAP, e - base);
        if (t < RPB) rcnt[t] = 0;
        if (t == RPB) roff[0] = 0;
        __syncthreads();
        int2 tmp[6];
#pragma unroll
        for (int j = 0; j < 6; ++j) {
            const int i = t + j * 256;
            if (i < cnt) {
                tmp[j] = edges[base + i];
                atomicAdd(&rcnt[tmp[j].x >> 17], 1);
            } else {
                tmp[j] = make_int2(0, 0);
            }
        }
        __syncthreads();
        if (t < 64) {
            const int v = rcnt[t];
            int inc = v;
#pragma unroll
            for (int d = 1; d < 64; d <<= 1) {
                const int u = __shfl_up(inc, d, 64);
                if (t >= d) inc += u;
            }
            roff[t + 1] = inc;
            rcur[t] = inc - v;
        }
        __syncthreads();
#pragma unroll
        for (int j = 0; j < 6; ++j) {
            const int i = t + j * 256;
            if (i < cnt) {
                const int rl = tmp[j].x >> 17;
                const int pos = atomicAdd(&rcur[rl], 1);
                sbuf[pos] = tmp[j];
            }
        }
        __syncthreads();
#pragma unroll
        for (int rr = 0; rr < 16; ++rr) {
            const int r = wave * 16 + rr;
            const int i0 = roff[r], i1 = roff[r + 1];
            float a0 = 0.f, a1 = 0.f, a2 = 0.f, a3 = 0.f;
            int i = i0;
            for (; i + 4 <= i1; i += 4) {
                const int2 e0 = sbuf[i];
                const int2 e1 = sbuf[i + 1];
                const int2 e2 = sbuf[i + 2];
                const int2 e3 = sbuf[i + 3];
                const float h0 = bf2f(hbf[(size_t)(e0.x & 0x1FFFF) * N_OUT + lane]);
                const float h1 = bf2f(hbf[(size_t)(e1.x & 0x1FFFF) * N_OUT + lane]);
                const float h2 = bf2f(hbf[(size_t)(e2.x & 0x1FFFF) * N_OUT + lane]);
                const float h3 = bf2f(hbf[(size_t)(e3.x & 0x1FFFF) * N_OUT + lane]);
                a0 = fmaf(__int_as_float(e0.y), h0, a0);
                a1 = fmaf(__int_as_float(e1.y), h1, a1);
                a2 = fmaf(__int_as_float(e2.y), h2, a2);
                a3 = fmaf(__int_as_float(e3.y), h3, a3);
            }
            for (; i < i1; ++i) {
                const int2 cv = sbuf[i];
                a0 = fmaf(__int_as_float(cv.y),
                          bf2f(hbf[(size_t)(cv.x & 0x1FFFF) * N_OUT + lane]), a0);
            }
            acc[rr] += (a0 + a1) + (a2 + a3);
        }
        __syncthreads();
    }

    const int row0 = b * RPB + wave * 16;
#pragma unroll
    for (int rr = 0; rr < 16; ++rr) {
        const int row = row0 + rr;
        if (row < N_NODES) {
            const float v = acc[rr];
            out[(size_t)row * N_OUT + lane] = v > 0.f ? v : expf(v) - 1.f;
        }
    }
}

extern "C" void kernel_launch(void* const* d_in, const int* in_sizes, int n_in,
                              void* d_out, int out_size, void* d_ws, size_t ws_size,
                              hipStream_t stream) {
    const float* x  = (const float*)d_in[0];
    const int*   er = (const int*)d_in[1];
    const int*   ec = (const int*)d_in[2];
    const float* ev = (const float*)d_in[3];
    const float* W  = (const float*)d_in[4];
    const float* b  = (const float*)d_in[5];
    float* out = (float*)d_out;
    char* ws = (char*)d_ws;

    unsigned short* hbf   = (unsigned short*)(ws + WS_HBF);
    unsigned short* wt    = (unsigned short*)(ws + WS_WT);
    unsigned short* gposT = (unsigned short*)(ws + WS_GP);
    unsigned short* histT = (unsigned short*)(ws + WS_HT);
    int*  btot  = (int*)(ws + WS_BTOT);
    int*  boffs = (int*)(ws + WS_BOFF);
    int2* edges = (int2*)(ws + WS_EDGES);

    hist2_kernel<<<NBLK, 256, 0, stream>>>(er, histT);
    scanA_kernel<<<(NBUCKETS + 3) / 4, 256, 0, stream>>>(histT, gposT, btot);
    bscan_kernel<<<1, 1024, 0, stream>>>(btot, boffs);
    scat2_kernel<<<NBLK, 256, 0, stream>>>(er, ec, ev, gposT, boffs, edges);
    wconv_kernel<<<64, 256, 0, stream>>>(W, wt);
    gemm_kernel<<<(N_NODES + 63) / 64, 256, 0, stream>>>(x, (const float4*)wt, b, hbf);
    bagg_kernel<<<NBUCKETS, 256, 0, stream>>>(boffs, edges, hbf, out);
}